// Round 1
// baseline (80.896 us; speedup 1.0000x reference)
//
#include <hip/hip_runtime.h>
#include <math.h>

#define BB 64
#define TT 2048
#define DD 512
#define HH 512
#define NEG_INF_F (-1e9f)

// ---------------------------------------------------------------------------
// Kernel 1: fused scores + online-softmax + partial context, one pass over enc.
// grid (NC, B), block 256 (4 waves). Each wave handles chunk_len/4 timesteps.
// Per lane d-mapping: float4 at d0 = lane*4 and d1 = 256 + lane*4.
// Writes per-(b,chunk) partial: ws_m[bc], ws_l[bc], ws_c[bc*512 + d].
// ---------------------------------------------------------------------------
__global__ __launch_bounds__(256) void k1_partial(
    const float* __restrict__ x, const float* __restrict__ enc,
    const int* __restrict__ step_ptr,
    float* __restrict__ ws_m, float* __restrict__ ws_l, float* __restrict__ ws_c,
    int NC)
{
    const int chunk = blockIdx.x;
    const int b     = blockIdx.y;
    const int tid   = threadIdx.x;
    const int w     = tid >> 6;
    const int lane  = tid & 63;
    const int step  = *step_ptr;
    const int chunk_len = TT / NC;
    const int t0    = chunk * chunk_len;

    // x fragments in registers (each lane always owns the same 8 dims)
    const float4* xr = (const float4*)(x + (size_t)b * DD);
    const float4 xa = xr[lane];        // dims lane*4 .. lane*4+3
    const float4 xb = xr[64 + lane];   // dims 256+lane*4 ..

    float m = -1e30f, l = 0.f;
    float4 ca = make_float4(0.f, 0.f, 0.f, 0.f);
    float4 cb = make_float4(0.f, 0.f, 0.f, 0.f);

    const float4* er = (const float4*)(enc + (size_t)b * TT * DD);

    for (int i = w; i < chunk_len; i += 4) {
        const int t = t0 + i;
        const float4* row = er + (size_t)t * (DD / 4);
        const float4 ea = row[lane];
        const float4 eb = row[64 + lane];

        float s = ea.x * xa.x + ea.y * xa.y + ea.z * xa.z + ea.w * xa.w
                + eb.x * xb.x + eb.y * xb.y + eb.z * xb.z + eb.w * xb.w;
        #pragma unroll
        for (int off = 32; off; off >>= 1) s += __shfl_xor(s, off, 64);

        const bool masked = (t == step);
        const float sm = masked ? NEG_INF_F : s;
        const float m_new = fmaxf(m, sm);
        const float scale = __expf(m - m_new);       // m_new >= m always
        const float wgt = masked ? 0.f : __expf(s - m_new);

        l = l * scale + wgt;
        ca.x = ca.x * scale + wgt * ea.x;
        ca.y = ca.y * scale + wgt * ea.y;
        ca.z = ca.z * scale + wgt * ea.z;
        ca.w = ca.w * scale + wgt * ea.w;
        cb.x = cb.x * scale + wgt * eb.x;
        cb.y = cb.y * scale + wgt * eb.y;
        cb.z = cb.z * scale + wgt * eb.z;
        cb.w = cb.w * scale + wgt * eb.w;
        m = m_new;
    }

    // ---- block combine of the 4 wave-partials via LDS ----
    __shared__ float ls_m[4], ls_l[4];
    __shared__ float ls_c[4][DD];
    if (lane == 0) { ls_m[w] = m; ls_l[w] = l; }
    {
        float* cw = ls_c[w];
        const int d0 = lane * 4;
        cw[d0 + 0] = ca.x; cw[d0 + 1] = ca.y; cw[d0 + 2] = ca.z; cw[d0 + 3] = ca.w;
        cw[256 + d0 + 0] = cb.x; cw[256 + d0 + 1] = cb.y;
        cw[256 + d0 + 2] = cb.z; cw[256 + d0 + 3] = cb.w;
    }
    __syncthreads();

    const float M = fmaxf(fmaxf(ls_m[0], ls_m[1]), fmaxf(ls_m[2], ls_m[3]));
    const float f0 = __expf(ls_m[0] - M);
    const float f1 = __expf(ls_m[1] - M);
    const float f2 = __expf(ls_m[2] - M);
    const float f3 = __expf(ls_m[3] - M);
    const float L = ls_l[0] * f0 + ls_l[1] * f1 + ls_l[2] * f2 + ls_l[3] * f3;

    const int bc = b * NC + chunk;
    for (int d = tid; d < DD; d += 256) {
        const float v = ls_c[0][d] * f0 + ls_c[1][d] * f1
                      + ls_c[2][d] * f2 + ls_c[3][d] * f3;
        ws_c[(size_t)bc * DD + d] = v;
    }
    if (tid == 0) { ws_m[bc] = M; ws_l[bc] = L; }
}

// ---------------------------------------------------------------------------
// Kernel 2: merge partials -> context, then gated gemm.
// grid (4, B), block 256. Each block: full concat=[x,context] in LDS,
// h-slice of 128 outputs, k-split-2 (tid>>7) with LDS pair-reduce.
// ---------------------------------------------------------------------------
__global__ __launch_bounds__(256) void k2_gemm(
    const float* __restrict__ x, const float* __restrict__ W,
    const float* __restrict__ bias,
    const float* __restrict__ ws_m, const float* __restrict__ ws_l,
    const float* __restrict__ ws_c,
    float* __restrict__ out, int NC)
{
    const int g   = blockIdx.x;
    const int b   = blockIdx.y;
    const int tid = threadIdx.x;

    __shared__ float concat[2 * DD];   // [ x | context ]
    __shared__ float part[256];

    // merge softmax partials (redundant per block; tiny, L2-resident)
    float M = -1e30f;
    for (int i = 0; i < NC; ++i) M = fmaxf(M, ws_m[b * NC + i]);
    float L = 0.f;
    for (int i = 0; i < NC; ++i) L += ws_l[b * NC + i] * __expf(ws_m[b * NC + i] - M);
    const float invL = 1.f / L;

    for (int d = tid; d < DD; d += 256) {
        concat[d] = x[(size_t)b * DD + d];
        float acc = 0.f;
        for (int i = 0; i < NC; ++i)
            acc += ws_c[(size_t)(b * NC + i) * DD + d] * __expf(ws_m[b * NC + i] - M);
        concat[DD + d] = acc * invL;
    }
    __syncthreads();

    // gemm slice: h in [g*128, g*128+128), k split in two halves of 512
    const int hl = tid & 127;
    const int kh = tid >> 7;
    const int h  = g * 128 + hl;
    const float* wp = W + (size_t)kh * 512 * HH + h;
    const float* cp = concat + kh * 512;
    float acc = 0.f;
    #pragma unroll 8
    for (int k = 0; k < 512; ++k)
        acc = fmaf(cp[k], wp[(size_t)k * HH], acc);
    part[tid] = acc;
    __syncthreads();

    if (tid < 128) {
        const float a = part[tid] + part[tid + 128] + bias[h];
        const float att = 1.f / (1.f + __expf(-a));
        out[(size_t)b * DD + h] = att * concat[h];   // x[h] lives in concat[0..511]
    }
}

// ---------------------------------------------------------------------------
extern "C" void kernel_launch(void* const* d_in, const int* in_sizes, int n_in,
                              void* d_out, int out_size, void* d_ws, size_t ws_size,
                              hipStream_t stream) {
    const float* x    = (const float*)d_in[0];
    const float* enc  = (const float*)d_in[1];
    const float* W    = (const float*)d_in[2];
    const float* bias = (const float*)d_in[3];
    const int*   step = (const int*)d_in[4];
    float* out = (float*)d_out;
    float* ws  = (float*)d_ws;

    // partials: m[B*NC] | l[B*NC] | c[B*NC*D]; shrink NC if ws is small
    int NC = 16;
    while (NC > 1 && (size_t)BB * NC * (DD + 2) * sizeof(float) > ws_size) NC >>= 1;

    float* ws_m = ws;
    float* ws_l = ws + (size_t)BB * NC;
    float* ws_c = ws + (size_t)2 * BB * NC;

    dim3 g1(NC, BB), blk(256);
    k1_partial<<<g1, blk, 0, stream>>>(x, enc, step, ws_m, ws_l, ws_c, NC);

    dim3 g2(4, BB);
    k2_gemm<<<g2, blk, 0, stream>>>(x, W, bias, ws_m, ws_l, ws_c, out, NC);
}

// Round 2
// 60.639 us; speedup vs baseline: 1.3341x; 1.3341x over previous
//
#include <hip/hip_runtime.h>
#include <math.h>

#define BB 64
#define TT 2048
#define DD 512
#define HH 512
#define NC 32                 // compile-time chunk count: CHUNK=64, grid 2048 blocks
#define CHUNK (TT / NC)       // 64 timesteps per block
#define TH 8.0f               // defer-rescale threshold (values bounded by e^8)

// ---------------------------------------------------------------------------
// Kernel 1: fused scores + deferred-rescale online-softmax + partial context.
// grid (NC, B), block 256 (4 waves). Wave w handles t = t0 + w + 4i, 16 iters.
// Lane d-mapping: float4 at d = lane*4 and d = 256 + lane*4.
// ---------------------------------------------------------------------------
__global__ __launch_bounds__(256) void k1_partial(
    const float* __restrict__ x, const float* __restrict__ enc,
    const int* __restrict__ step_ptr,
    float* __restrict__ ws_m, float* __restrict__ ws_l, float* __restrict__ ws_c)
{
    const int chunk = blockIdx.x;
    const int b     = blockIdx.y;
    const int tid   = threadIdx.x;
    const int w     = tid >> 6;
    const int lane  = tid & 63;
    const int step  = *step_ptr;
    const int t0    = chunk * CHUNK;

    const float4* xr = (const float4*)(x + (size_t)b * DD);
    const float4 xa = xr[lane];
    const float4 xb = xr[64 + lane];

    float m = -1e30f, l = 0.f;
    float4 ca = make_float4(0.f, 0.f, 0.f, 0.f);
    float4 cb = make_float4(0.f, 0.f, 0.f, 0.f);

    const float4* er = (const float4*)(enc + (size_t)b * TT * DD);

    #pragma unroll 4
    for (int i = w; i < CHUNK; i += 4) {
        const int t = t0 + i;
        const float4* row = er + (size_t)t * (DD / 4);
        const float4 ea = row[lane];
        const float4 eb = row[64 + lane];

        float s = ea.x * xa.x + ea.y * xa.y + ea.z * xa.z + ea.w * xa.w
                + eb.x * xb.x + eb.y * xb.y + eb.z * xb.z + eb.w * xb.w;
        #pragma unroll
        for (int off = 32; off; off >>= 1) s += __shfl_xor(s, off, 64);

        // s is wave-uniform; branches below are non-divergent.
        if (t != step) {
            float wgt;
            if (s > m + TH) {                 // rare: rescale accumulators
                const float sc = __expf(m - s);
                l *= sc;
                ca.x *= sc; ca.y *= sc; ca.z *= sc; ca.w *= sc;
                cb.x *= sc; cb.y *= sc; cb.z *= sc; cb.w *= sc;
                m = s;
                wgt = 1.f;
            } else {                          // common: accumulate only
                wgt = __expf(s - m);
            }
            l += wgt;
            ca.x = fmaf(wgt, ea.x, ca.x);
            ca.y = fmaf(wgt, ea.y, ca.y);
            ca.z = fmaf(wgt, ea.z, ca.z);
            ca.w = fmaf(wgt, ea.w, ca.w);
            cb.x = fmaf(wgt, eb.x, cb.x);
            cb.y = fmaf(wgt, eb.y, cb.y);
            cb.z = fmaf(wgt, eb.z, cb.z);
            cb.w = fmaf(wgt, eb.w, cb.w);
        }
    }

    // ---- block combine of the 4 wave-partials via LDS ----
    __shared__ float ls_m[4], ls_l[4];
    __shared__ float ls_c[4][DD];
    if (lane == 0) { ls_m[w] = m; ls_l[w] = l; }
    {
        float* cw = ls_c[w];
        const int d0 = lane * 4;
        cw[d0 + 0] = ca.x; cw[d0 + 1] = ca.y; cw[d0 + 2] = ca.z; cw[d0 + 3] = ca.w;
        cw[256 + d0 + 0] = cb.x; cw[256 + d0 + 1] = cb.y;
        cw[256 + d0 + 2] = cb.z; cw[256 + d0 + 3] = cb.w;
    }
    __syncthreads();

    const float M = fmaxf(fmaxf(ls_m[0], ls_m[1]), fmaxf(ls_m[2], ls_m[3]));
    const float f0 = __expf(ls_m[0] - M);
    const float f1 = __expf(ls_m[1] - M);
    const float f2 = __expf(ls_m[2] - M);
    const float f3 = __expf(ls_m[3] - M);
    const float L = ls_l[0] * f0 + ls_l[1] * f1 + ls_l[2] * f2 + ls_l[3] * f3;

    const int bc = b * NC + chunk;
    for (int d = tid; d < DD; d += 256) {
        const float v = ls_c[0][d] * f0 + ls_c[1][d] * f1
                      + ls_c[2][d] * f2 + ls_c[3][d] * f3;
        ws_c[(size_t)bc * DD + d] = v;
    }
    if (tid == 0) { ws_m[bc] = M; ws_l[bc] = L; }
}

// ---------------------------------------------------------------------------
// Kernel 2: merge partials -> context in LDS, then gated gemm with float4 W.
// grid (8, B), block 256. Block g covers 64 h (16 float4 cols), k-split 16.
// ---------------------------------------------------------------------------
__global__ __launch_bounds__(256) void k2_gemm(
    const float* __restrict__ x, const float* __restrict__ W,
    const float* __restrict__ bias,
    const float* __restrict__ ws_m, const float* __restrict__ ws_l,
    const float* __restrict__ ws_c,
    float* __restrict__ out)
{
    const int g   = blockIdx.x;     // 0..7
    const int b   = blockIdx.y;
    const int tid = threadIdx.x;

    __shared__ float concat[2 * DD];     // [ x | context ]
    __shared__ float fac[NC];
    __shared__ float4 part[256];

    // softmax merge factors (redundant per thread; addresses wave-uniform)
    float M = -1e30f;
    #pragma unroll
    for (int i = 0; i < NC; ++i) M = fmaxf(M, ws_m[b * NC + i]);
    float L = 0.f;
    #pragma unroll
    for (int i = 0; i < NC; ++i) L += ws_l[b * NC + i] * __expf(ws_m[b * NC + i] - M);
    const float invL = 1.f / L;
    if (tid < NC) fac[tid] = __expf(ws_m[b * NC + tid] - M);
    __syncthreads();

    for (int d = tid; d < DD; d += 256) {
        concat[d] = x[(size_t)b * DD + d];
        float acc = 0.f;
        #pragma unroll 8
        for (int i = 0; i < NC; ++i)
            acc = fmaf(ws_c[(size_t)(b * NC + i) * DD + d], fac[i], acc);
        concat[DD + d] = acc * invL;
    }
    __syncthreads();

    // gemm: thread = (kq, cl); col4 = g*16+cl covers h = col4*4..+3
    const int cl   = tid & 15;
    const int kq   = tid >> 4;           // 0..15, k-range [kq*64, kq*64+64)
    const int col4 = g * 16 + cl;
    const float4* W4 = (const float4*)W; // [1024][128] float4 row-major

    float4 acc = make_float4(0.f, 0.f, 0.f, 0.f);
    const int kbase = kq * 64;
    #pragma unroll 8
    for (int kk = 0; kk < 64; ++kk) {
        const int k = kbase + kk;
        const float4 wv = W4[(size_t)k * (HH / 4) + col4];
        const float cv = concat[k];
        acc.x = fmaf(cv, wv.x, acc.x);
        acc.y = fmaf(cv, wv.y, acc.y);
        acc.z = fmaf(cv, wv.z, acc.z);
        acc.w = fmaf(cv, wv.w, acc.w);
    }
    part[tid] = acc;
    __syncthreads();

    // reduce over kq (16 -> 1)
    #pragma unroll
    for (int s = 8; s; s >>= 1) {
        if (kq < s) {
            const float4 o = part[(kq + s) * 16 + cl];
            acc.x += o.x; acc.y += o.y; acc.z += o.z; acc.w += o.w;
            part[tid] = acc;
        }
        __syncthreads();
    }

    if (kq == 0) {
        const int h = col4 * 4;          // < 512
        const float4 bv = *(const float4*)(bias + h);
        const float4 xv = *(const float4*)(concat + h);   // x[h..h+3]
        float4 r;
        r.x = xv.x / (1.f + __expf(-(acc.x + bv.x)));
        r.y = xv.y / (1.f + __expf(-(acc.y + bv.y)));
        r.z = xv.z / (1.f + __expf(-(acc.z + bv.z)));
        r.w = xv.w / (1.f + __expf(-(acc.w + bv.w)));
        *(float4*)(out + (size_t)b * DD + h) = r;
    }
}

// ---------------------------------------------------------------------------
extern "C" void kernel_launch(void* const* d_in, const int* in_sizes, int n_in,
                              void* d_out, int out_size, void* d_ws, size_t ws_size,
                              hipStream_t stream) {
    const float* x    = (const float*)d_in[0];
    const float* enc  = (const float*)d_in[1];
    const float* W    = (const float*)d_in[2];
    const float* bias = (const float*)d_in[3];
    const int*   step = (const int*)d_in[4];
    float* out = (float*)d_out;
    float* ws  = (float*)d_ws;

    float* ws_m = ws;                          // [B*NC]
    float* ws_l = ws + (size_t)BB * NC;        // [B*NC]
    float* ws_c = ws + (size_t)2 * BB * NC;    // [B*NC*D]

    dim3 g1(NC, BB), blk(256);
    k1_partial<<<g1, blk, 0, stream>>>(x, enc, step, ws_m, ws_l, ws_c);

    dim3 g2(8, BB);
    k2_gemm<<<g2, blk, 0, stream>>>(x, W, bias, ws_m, ws_l, ws_c, out);
}